// Round 5
// baseline (364.524 us; speedup 1.0000x reference)
//
#include <hip/hip_runtime.h>

typedef unsigned int u32;
typedef unsigned short u16;
typedef float f32x4 __attribute__((ext_vector_type(4)));
typedef __bf16 bf16x8 __attribute__((ext_vector_type(8)));

#define BATCH 128
#define NIN   1024
#define DIN   256
#define NC    16
#define DC    32
#define NCOL  512

__device__ __forceinline__ float bflo(u32 v){ return __uint_as_float(v << 16); }
__device__ __forceinline__ float bfhi(u32 v){ return __uint_as_float(v & 0xffff0000u); }
__device__ __forceinline__ u32 bfround(u32 ua){ return (ua + 0x7fffu + ((ua >> 16) & 1u)) >> 16; }
__device__ __forceinline__ u32 pack2(float a, float b){
    return (bfround(__float_as_uint(a)) & 0xffffu) | (bfround(__float_as_uint(b)) << 16);
}
__device__ __forceinline__ bf16x8 ldfrag(const u16* p){
    return __builtin_bit_cast(bf16x8, *(const uint4*)p);
}

// Swizzled address (bf16 units) for a [64][256] bf16 LDS tile.
// Verified (rounds 0-4) for 8B/16B row-chunk writes and column u16 gathers.
__device__ __forceinline__ int lds_x(int r, int d){
    int sw = (d >> 2) ^ ((r & 7) << 1) ^ (((r >> 3) & 3) << 2);
    return r * 256 + (sw << 2) + (d & 3);
}

// K0: per (b, 64-row j-chunk):
//   xb  : row-major bf16 x [b][j][d]     (16B coalesced stores)
//   xbT : j-contiguous MFMA B-fragment order uint4[((b*16+dt)*32+js)*64+lane],
//         lane(l15,q) = x[js*32+q*8 .. +7][dt*16+l15]
//   s   : += column sums (LDS-reduced, 1 atomic per d per block)
//   Wb/WT : bf16 W and W^T (blocks with jc==0)
__global__ __launch_bounds__(256) void k_pre(const float* __restrict__ x, const float* __restrict__ W,
                                             uint4* __restrict__ xbT, u16* __restrict__ xb,
                                             float* __restrict__ s, uint2* __restrict__ Wb,
                                             uint2* __restrict__ WT){
    __shared__ __align__(16) u16 xt[64 * 256];   // 32 KB
    __shared__ float csum[8][256];               //  8 KB
    const int t = threadIdx.x, jc = blockIdx.x, b = blockIdx.y;

    if (jc == 0){   // W conversions: 128 (b) blocks cover all of W
        int id = b * 256 + t;
        float4 w4 = ((const float4*)W)[id];
        Wb[id] = make_uint2(pack2(w4.x, w4.y), pack2(w4.z, w4.w));
        int c = id >> 6, d4 = id & 63;           // WT[c][4*d4 .. +3]
        float e0 = W[(size_t)(d4 * 4 + 0) * NCOL + c];
        float e1 = W[(size_t)(d4 * 4 + 1) * NCOL + c];
        float e2 = W[(size_t)(d4 * 4 + 2) * NCOL + c];
        float e3 = W[(size_t)(d4 * 4 + 3) * NCOL + c];
        WT[c * 64 + d4] = make_uint2(pack2(e0, e1), pack2(e2, e3));
    }
    {   // stage 64x256: thread owns (r0 = t>>5, cols d8*8..+7); rows r0+8m
        const float4* xg = (const float4*)(x + ((size_t)b * NIN + jc * 64) * DIN);
        uint4* xbw = (uint4*)(xb + ((size_t)(b * NIN + jc * 64)) * 256);
        int d8 = t & 31, r0 = t >> 5;
        float cs[8];
        #pragma unroll
        for (int e = 0; e < 8; e++) cs[e] = 0.f;
        #pragma unroll
        for (int m = 0; m < 8; m++){
            int r = r0 + 8 * m;
            float4 a = xg[r * 64 + 2 * d8], c4 = xg[r * 64 + 2 * d8 + 1];
            uint4 p = make_uint4(pack2(a.x, a.y), pack2(a.z, a.w),
                                 pack2(c4.x, c4.y), pack2(c4.z, c4.w));
            *(uint4*)&xt[lds_x(r, d8 * 8)] = p;
            xbw[r * 32 + d8] = p;
            cs[0] += bflo(p.x); cs[1] += bfhi(p.x);
            cs[2] += bflo(p.y); cs[3] += bfhi(p.y);
            cs[4] += bflo(p.z); cs[5] += bfhi(p.z);
            cs[6] += bflo(p.w); cs[7] += bfhi(p.w);
        }
        *(float4*)&csum[r0][d8 * 8]     = make_float4(cs[0], cs[1], cs[2], cs[3]);
        *(float4*)&csum[r0][d8 * 8 + 4] = make_float4(cs[4], cs[5], cs[6], cs[7]);
    }
    __syncthreads();
    {   // col-sum finalize: one atomic per d per block (16 contenders per address)
        float acc = 0.f;
        #pragma unroll
        for (int r0 = 0; r0 < 8; r0++) acc += csum[r0][t];
        atomicAdd(&s[b * DIN + t], acc);
    }
    // transpose gather -> xbT (verbatim round-2, 8 uint4 per thread)
    #pragma unroll
    for (int w = 0; w < 8; w++){
        int oid = t + 256 * w;                    // 0..2047
        int lane = oid & 63, js2 = (oid >> 6) & 1, dt = oid >> 7;
        int l15 = lane & 15, q = lane >> 4;
        int rb = js2 * 32 + q * 8, d = dt * 16 + l15;
        u32 r[4];
        #pragma unroll
        for (int p = 0; p < 4; p++){
            u32 lo = xt[lds_x(rb + 2 * p, d)];
            u32 hi = xt[lds_x(rb + 2 * p + 1, d)];
            r[p] = lo | (hi << 16);
        }
        xbT[(((size_t)b * 16 + dt) * 32 + (jc * 2 + js2)) * 64 + lane] = make_uint4(r[0], r[1], r[2], r[3]);
    }
}

// K1: per (b, 128-row j-chunk), 512 threads / 8 waves, tiny LDS (full occupancy):
//     bb = v.x^T (A=v frags, B=xb rows); softmax over i; z partial = c.xbT -> zp.
__global__ __launch_bounds__(512) void k_main(const u16* __restrict__ xb, const uint4* __restrict__ xbT,
                                              const u16* __restrict__ vb, float* __restrict__ zp){
    __shared__ float bbl[16][132];                //  8.25 KB
    __shared__ __align__(16) u16 cl[16][136];     //  4.25 KB
    const int t = threadIdx.x, jh = blockIdx.x, b = blockIdx.y;
    const int lane = t & 63, wv = t >> 6;         // 8 waves
    const int l15 = lane & 15, q = lane >> 4;

    // v A-fragments: lane(l15,q) = vb[b][i=l15][ks*32+q*8 .. +7]
    uint4 vf[8];
    #pragma unroll
    for (int ks = 0; ks < 8; ks++)
        vf[ks] = *(const uint4*)&vb[((size_t)b * 16 + l15) * 256 + ks * 32 + q * 8];

    // phase A: bb[i,j]; wave wv owns j-tile jt = wv
    {
        const u16* xr = xb + ((size_t)(b * NIN + jh * 128 + wv * 16 + l15)) * 256 + q * 8;
        f32x4 acc = {0.f, 0.f, 0.f, 0.f};
        #pragma unroll
        for (int ks = 0; ks < 8; ks++)
            acc = __builtin_amdgcn_mfma_f32_16x16x32_bf16(
                __builtin_bit_cast(bf16x8, vf[ks]), ldfrag(xr + ks * 32), acc, 0, 0, 0);
        #pragma unroll
        for (int r = 0; r < 4; r++) bbl[q * 4 + r][wv * 16 + l15] = acc[r];   // row=i, col=j
    }
    __syncthreads();

    // phase B: softmax over i per column j
    if (t < 128){
        float mx = -1e30f, e[16], sum = 0.f;
        #pragma unroll
        for (int i = 0; i < 16; i++) mx = fmaxf(mx, bbl[i][t]);
        #pragma unroll
        for (int i = 0; i < 16; i++){ e[i] = __expf(bbl[i][t] - mx); sum += e[i]; }
        float inv = 1.f / sum;
        #pragma unroll
        for (int i = 0; i < 16; i++) cl[i][t] = (u16)bfround(__float_as_uint(e[i] * inv));
    }
    __syncthreads();

    // phase C: z partial; wave wv owns d-tiles dt = wv*2 + u
    bf16x8 cfrag[4];
    #pragma unroll
    for (int ksj = 0; ksj < 4; ksj++)
        cfrag[ksj] = ldfrag(&cl[l15][ksj * 32 + q * 8]);
    #pragma unroll
    for (int u = 0; u < 2; u++){
        int dt = wv * 2 + u;
        f32x4 acc = {0.f, 0.f, 0.f, 0.f};
        #pragma unroll
        for (int ksj = 0; ksj < 4; ksj++){
            uint4 bw = xbT[(((size_t)b * 16 + dt) * 32 + jh * 4 + ksj) * 64 + lane];
            acc = __builtin_amdgcn_mfma_f32_16x16x32_bf16(
                cfrag[ksj], __builtin_bit_cast(bf16x8, bw), acc, 0, 0, 0);
        }
        float* zpb = zp + ((((size_t)jh * 128 + b) * 16) * 256) + dt * 16 + l15;
        #pragma unroll
        for (int r = 0; r < 4; r++) zpb[(size_t)(q * 4 + r) * 256] = acc[r];
    }
}

// K2: per (b, half): 8 capsules. y = z.W, squash, v = o.W via WT. (round-2 verified)
__global__ __launch_bounds__(256) void k_tail(const float* __restrict__ s, const float* __restrict__ zp,
                                              const u16* __restrict__ Wb, const u32* __restrict__ WT32,
                                              u16* __restrict__ vb, float* __restrict__ out, int mode){
    __shared__ float zl[8][260];
    __shared__ __align__(16) float ol[256];
    const int ih2 = blockIdx.x, b = blockIdx.y, t = threadIdx.x;
    const int i_loc = t >> 5;                     // 0..7
    const int o_idx = ih2 * 256 + t;              // global (i,k) flat index
    float y = 0.f;
    if (mode == 0){
        zl[0][t] = s[b * 256 + t] * (1.f / 16.f);
        __syncthreads();
        #pragma unroll 8
        for (int d = 0; d < 256; d++) y += zl[0][d] * bflo((u32)Wb[d * 512 + o_idx]);
    } else {
        #pragma unroll
        for (int u0 = 0; u0 < 8; u0++){
            int idx = t + 256 * u0;               // (ii, dd) over 8x256
            int ii = idx >> 8, dd = idx & 255;
            int ig = ih2 * 8 + ii;
            float acc = 0.f;
            #pragma unroll
            for (int jh = 0; jh < 8; jh++)
                acc += zp[((((size_t)jh * 128 + b) * 16 + ig) * 256) + dd];
            zl[ii][dd] = acc;
        }
        __syncthreads();
        #pragma unroll 8
        for (int d = 0; d < 256; d++) y += zl[i_loc][d] * bflo((u32)Wb[d * 512 + o_idx]);
    }
    // squash (unit-norm over the 32 k-lanes of each capsule)
    float s2 = y * y;
    s2 += __shfl_xor(s2, 1); s2 += __shfl_xor(s2, 2); s2 += __shfl_xor(s2, 4);
    s2 += __shfl_xor(s2, 8); s2 += __shfl_xor(s2, 16);
    float r = y / sqrtf(s2 + 1e-7f);
    if (mode == 2){ out[b * 512 + o_idx] = r; return; }
    ol[t] = r;
    __syncthreads();
    // v-pass: thread owns d-pair dh; 4 capsules of this half (coalesced WT reads)
    {
        int dh = t & 127, ihalf = t >> 7;
        #pragma unroll
        for (int e = 0; e < 4; e++){
            int ii = ihalf * 4 + e;
            int i2 = ih2 * 8 + ii;
            float a0 = 0.f, a1 = 0.f;
            #pragma unroll
            for (int k = 0; k < 32; k++){
                u32 wv2 = WT32[(size_t)(i2 * 32 + k) * 128 + dh];
                float ok = ol[ii * 32 + k];
                a0 += ok * bflo(wv2); a1 += ok * bfhi(wv2);
            }
            ((u32*)vb)[(size_t)(b * 16 + i2) * 128 + dh] = pack2(a0, a1);
        }
    }
}

extern "C" void kernel_launch(void* const* d_in, const int* in_sizes, int n_in,
                              void* d_out, int out_size, void* d_ws, size_t ws_size,
                              hipStream_t stream){
    const float* x = (const float*)d_in[0];    // fp32 [128][1024][256]
    const float* W = (const float*)d_in[1];    // fp32 [256][512]
    float* out = (float*)d_out;                // fp32 [128][16][32]
    char* ws = (char*)d_ws;                    // ~153 MB used
    float* s    = (float*)(ws);                //    131,072 B : column sums
    u16*   Wb   = (u16*)  (ws + 131072);       //    262,144 B : W bf16 [d][c]
    u32*   WT   = (u32*)  (ws + 393216);       //    262,144 B : W^T bf16 [c][d]
    u16*   vb   = (u16*)  (ws + 655360);       //  1,048,576 B : v = o.W-slices, bf16
    float* zp   = (float*)(ws + 1703936);      // 16,777,216 B : z partials [8][128][16][256]
    u16*   xb   = (u16*)  (ws + 18481152);     // 67,108,864 B : x bf16 row-major
    uint4* xbT  = (uint4*)(ws + 85590016);     // 67,108,864 B : x bf16 j-contiguous frag order

    hipMemsetAsync(s, 0, 131072, stream);
    k_pre<<<dim3(16, BATCH), 256, 0, stream>>>(x, W, xbT, xb, s, (uint2*)Wb, (uint2*)WT);
    k_tail<<<dim3(2, BATCH), 256, 0, stream>>>(s, zp, Wb, WT, vb, out, 0);
    for (int it = 1; it < 4; it++){
        k_main<<<dim3(8, BATCH), 512, 0, stream>>>(xb, xbT, vb, zp);
        k_tail<<<dim3(2, BATCH), 256, 0, stream>>>(s, zp, Wb, WT, vb, out, it == 3 ? 2 : 1);
    }
}